// Round 1
// baseline (767.627 us; speedup 1.0000x reference)
//
#include <hip/hip_runtime.h>
#include <hip/hip_bf16.h>

#define E_TOTAL   1600000
#define NV        50000
#define DE        64
#define DV        64
#define DIN       192
#define DHID      128
#define DOUT      64
#define TILE_M    64
#define XS        200          // xb row stride (ushorts), 400 B -> bank walk 4/l15 (min aliasing)
#define HS        136          // hb row stride (ushorts), 272 B -> bank walk 4/l15 (min aliasing)
#define NTILES    (E_TOTAL / TILE_M)   // 25000 exact

typedef __bf16 bf16x8  __attribute__((ext_vector_type(8)));
typedef __bf16 bf16x4  __attribute__((ext_vector_type(4)));
typedef float  floatx4 __attribute__((ext_vector_type(4)));
typedef float  fx4     __attribute__((ext_vector_type(4)));

static __device__ __forceinline__ unsigned short f2bf(float f) {
    unsigned int u = __float_as_uint(f);
    u += 0x7fffu + ((u >> 16) & 1u);   // round-to-nearest-even
    return (unsigned short)(u >> 16);
}

// ---- prep: W1 [192][128] -> w1t bf16 [128][192]; W2 [128][64] -> w2t bf16 [64][128];
//      vfeat fp32 [NV][64] -> vfb bf16 (same layout)
__global__ void prep_kernel(const float* __restrict__ W1, const float* __restrict__ W2,
                            const float* __restrict__ vfeat,
                            unsigned short* __restrict__ w1t,
                            unsigned short* __restrict__ w2t,
                            unsigned short* __restrict__ vfb, int do_vfb) {
    int tid = blockIdx.x * blockDim.x + threadIdx.x;
    int stride = gridDim.x * blockDim.x;
    for (int i = tid; i < DIN * DHID; i += stride) {
        int n = i / DIN, k = i % DIN;
        w1t[i] = f2bf(W1[k * DHID + n]);
    }
    for (int i = tid; i < DHID * DOUT; i += stride) {
        int n = i / DHID, k = i % DHID;
        w2t[i] = f2bf(W2[k * DOUT + n]);
    }
    if (do_vfb) {
        const fx4* src = (const fx4*)vfeat;
        ushort4* dst = (ushort4*)vfb;
        int n4 = NV * DV / 4;
        for (int i = tid; i < n4; i += stride) {
            fx4 v = src[i];
            ushort4 o;
            o.x = f2bf(v[0]); o.y = f2bf(v[1]); o.z = f2bf(v[2]); o.w = f2bf(v[3]);
            dst[i] = o;
        }
    }
}

// Structure (per grid-stride iteration, 2 barriers/tile, T14 async-stage):
//   issue idx(t+1) + edata(t+1) -> regs          (VMEM in flight under L1)
//   L1: h^T = mfma(W1^T-frag, x-frag)            (swap trick: lane holds 4 consecutive k of h)
//   relu + pack -> ds_write_b64 into hb[e][k]    (k-contiguous, no transpose needed)
//   issue gathers(t+1) (idx arrived during L1)
//   __syncthreads()
//   L2: out^T = mfma(W2^T-frag, h-frag)          (lane holds 4 consecutive out floats)
//   global_store_dwordx4 out(t)
//   write xb <- staged regs (t+1)
//   __syncthreads()
template <bool USE_VFB>
__global__ __launch_bounds__(256, 2) void edge_mlp(
    const float* __restrict__ edata,
    const float* __restrict__ vfeat,
    const float* __restrict__ b1,
    const float* __restrict__ b2,
    const int* __restrict__ senders,
    const int* __restrict__ receivers,
    const unsigned short* __restrict__ w1t,
    const unsigned short* __restrict__ w2t,
    const unsigned short* __restrict__ vfb,
    float* __restrict__ out) {
    __shared__ unsigned short xb[TILE_M * XS];   // 25600 B
    __shared__ unsigned short hb[TILE_M * HS];   // 17408 B

    const int tid  = threadIdx.x;
    const int lane = tid & 63;
    const int wave = tid >> 6;
    const int l15  = lane & 15;
    const int quad = lane >> 4;

    // ---- per-wave weight fragments in registers.
    // These load exactly the MFMA *A*-operand layout: lane&15 = row, k = quad*8+j.
    bf16x8 w1f[6][2];   // rows n = wave*32 + nb*16 + l15 of W1^T [128][192]
    bf16x8 w2f[4];      // rows n = wave*16 + l15 of W2^T [64][128]
    {
        for (int nb = 0; nb < 2; ++nb) {
            int n = wave * 32 + nb * 16 + l15;
            const unsigned short* p = w1t + n * DIN + quad * 8;
            for (int ks = 0; ks < 6; ++ks)
                w1f[ks][nb] = *(const bf16x8*)(p + ks * 32);
        }
        int n2 = wave * 16 + l15;
        const unsigned short* p2 = w2t + n2 * DHID + quad * 8;
        for (int ks = 0; ks < 4; ++ks)
            w2f[ks] = *(const bf16x8*)(p2 + ks * 32);
    }
    // With swapped operands, C row = quad*4 + r indexes the *n* dimension.
    float b1v[2][4], b2v[4];
#pragma unroll
    for (int nb = 0; nb < 2; ++nb)
#pragma unroll
        for (int r = 0; r < 4; ++r)
            b1v[nb][r] = b1[wave * 32 + nb * 16 + quad * 4 + r];
#pragma unroll
    for (int r = 0; r < 4; ++r)
        b2v[r] = b2[wave * 16 + quad * 4 + r];

    // ---- staged-register buffers for tile t+1
    int   rix[4];    // vfb path: one vertex-row index per (e,g) chunk
    fx4   ed[4];     // edata: 4x fx4 per thread
    uint4 gv[4];     // vfb path: 4x 16B bf16 gather chunks
    int   rix8[8];   // fp32 fallback path
    fx4   gf[8];

    auto issue_idx = [&](long eb) {
        if constexpr (USE_VFB) {
#pragma unroll
            for (int it = 0; it < 4; ++it) {
                int idx = it * 256 + tid;
                int e = idx >> 4, g = (idx >> 3) & 1;
                rix[it] = (g ? senders : receivers)[eb + e];
            }
        } else {
#pragma unroll
            for (int it = 0; it < 8; ++it) {
                int idx = it * 256 + tid;
                int e = idx >> 5, g = (idx >> 4) & 1;
                rix8[it] = (g ? senders : receivers)[eb + e];
            }
        }
    };
    auto issue_edata = [&](long eb) {
#pragma unroll
        for (int it = 0; it < 4; ++it) {
            int idx = it * 256 + tid;
            int e = idx >> 4, c = idx & 15;
            ed[it] = __builtin_nontemporal_load((const fx4*)(edata + (eb + e) * DE + c * 4));
        }
    };
    auto issue_gather = [&]() {
        if constexpr (USE_VFB) {
#pragma unroll
            for (int it = 0; it < 4; ++it) {
                int idx = it * 256 + tid;
                int c = idx & 7;
                gv[it] = *(const uint4*)(vfb + rix[it] * DV + c * 8);
            }
        } else {
#pragma unroll
            for (int it = 0; it < 8; ++it) {
                int idx = it * 256 + tid;
                int c = idx & 15;
                gf[it] = *(const fx4*)(vfeat + (long)rix8[it] * DV + c * 4);
            }
        }
    };
    auto write_xb = [&]() {
        // edata fp32 -> bf16 (RNE via native cast; compiler packs to v_cvt_pk_bf16_f32)
#pragma unroll
        for (int it = 0; it < 4; ++it) {
            int idx = it * 256 + tid;
            int e = idx >> 4, c = idx & 15;
            fx4 v = ed[it];
            bf16x4 o;
            o[0] = (__bf16)v[0]; o[1] = (__bf16)v[1];
            o[2] = (__bf16)v[2]; o[3] = (__bf16)v[3];
            *(bf16x4*)(xb + e * XS + c * 4) = o;
        }
        if constexpr (USE_VFB) {
#pragma unroll
            for (int it = 0; it < 4; ++it) {
                int idx = it * 256 + tid;
                int e = idx >> 4, g = (idx >> 3) & 1, c = idx & 7;
                *(uint4*)(xb + e * XS + DE + g * DV + c * 8) = gv[it];
            }
        } else {
#pragma unroll
            for (int it = 0; it < 8; ++it) {
                int idx = it * 256 + tid;
                int e = idx >> 5, g = (idx >> 4) & 1, c = idx & 15;
                fx4 v = gf[it];
                bf16x4 o;
                o[0] = (__bf16)v[0]; o[1] = (__bf16)v[1];
                o[2] = (__bf16)v[2]; o[3] = (__bf16)v[3];
                *(bf16x4*)(xb + e * XS + DE + g * DV + c * 4) = o;
            }
        }
    };

    int t = blockIdx.x;

    // ---- prologue: stage tile t (latency exposed once per block)
    issue_idx((long)t * TILE_M);
    issue_edata((long)t * TILE_M);
    issue_gather();
    write_xb();
    __syncthreads();

    while (true) {
        const long eb0 = (long)t * TILE_M;
        const int tn = t + (int)gridDim.x;
        const bool has_next = tn < NTILES;

        if (has_next) {
            issue_idx((long)tn * TILE_M);
            issue_edata((long)tn * TILE_M);
            __builtin_amdgcn_sched_barrier(0);   // keep the prefetch issues above L1
        }

        // ---- layer 1: C = mfma(W1^T-frag, x-frag) -> lane holds h[e][k0..k0+3]
        floatx4 acc[4][2];
#pragma unroll
        for (int mb = 0; mb < 4; ++mb)
#pragma unroll
            for (int nb = 0; nb < 2; ++nb)
                acc[mb][nb] = (floatx4){b1v[nb][0], b1v[nb][1], b1v[nb][2], b1v[nb][3]};
        __builtin_amdgcn_s_setprio(1);
#pragma unroll
        for (int ks = 0; ks < 6; ++ks) {
            bf16x8 a[4];
#pragma unroll
            for (int mb = 0; mb < 4; ++mb)
                a[mb] = *(const bf16x8*)(xb + (mb * 16 + l15) * XS + ks * 32 + quad * 8);
#pragma unroll
            for (int mb = 0; mb < 4; ++mb)
#pragma unroll
                for (int nb = 0; nb < 2; ++nb)
                    acc[mb][nb] = __builtin_amdgcn_mfma_f32_16x16x32_bf16(
                        w1f[ks][nb], a[mb], acc[mb][nb], 0, 0, 0);
        }
        __builtin_amdgcn_s_setprio(0);

        // relu + pack: lane (quad,l15) holds h[mb*16+l15][wave*32+nb*16+quad*4 + r]
        // -> 4 consecutive k => single 8-B LDS write, k-contiguous hb[64][HS]
#pragma unroll
        for (int mb = 0; mb < 4; ++mb)
#pragma unroll
            for (int nb = 0; nb < 2; ++nb) {
                bf16x4 o;
#pragma unroll
                for (int r = 0; r < 4; ++r) {
                    float v = acc[mb][nb][r];
                    o[r] = (__bf16)(v > 0.f ? v : 0.f);
                }
                *(bf16x4*)(hb + (mb * 16 + l15) * HS + wave * 32 + nb * 16 + quad * 4) = o;
            }

        if (has_next) {
            issue_gather();                      // idx landed during L1
            __builtin_amdgcn_sched_barrier(0);   // keep gather issues above the barrier
        }

        __syncthreads();   // hb ready; xb(t) reads done

        // ---- layer 2: C = mfma(W2^T-frag, h-frag) -> lane holds out[e][n0..n0+3]
        floatx4 acc2[4];
#pragma unroll
        for (int mb = 0; mb < 4; ++mb)
            acc2[mb] = (floatx4){b2v[0], b2v[1], b2v[2], b2v[3]};
        __builtin_amdgcn_s_setprio(1);
#pragma unroll
        for (int ks = 0; ks < 4; ++ks)
#pragma unroll
            for (int mb = 0; mb < 4; ++mb) {
                bf16x8 a2 = *(const bf16x8*)(hb + (mb * 16 + l15) * HS + ks * 32 + quad * 8);
                acc2[mb] = __builtin_amdgcn_mfma_f32_16x16x32_bf16(w2f[ks], a2, acc2[mb], 0, 0, 0);
            }
        __builtin_amdgcn_s_setprio(0);

        // store: 16B vectorized; wave covers rows mb*16+l15, 64-B column slice wave*64
#pragma unroll
        for (int mb = 0; mb < 4; ++mb)
            __builtin_nontemporal_store(acc2[mb],
                (fx4*)(out + (eb0 + mb * 16 + l15) * DOUT + wave * 16 + quad * 4));

        if (!has_next) break;

        write_xb();        // commit tile t+1 (vmcnt waits happen here, after L2 hid latency)
        __syncthreads();   // xb(t+1) ready; hb(t) reads done before next L1 overwrites
        t = tn;
    }
}

extern "C" void kernel_launch(void* const* d_in, const int* in_sizes, int n_in,
                              void* d_out, int out_size, void* d_ws, size_t ws_size,
                              hipStream_t stream) {
    const float* edata     = (const float*)d_in[0];
    const float* vfeat     = (const float*)d_in[1];
    const float* W1        = (const float*)d_in[2];
    const float* b1        = (const float*)d_in[3];
    const float* W2        = (const float*)d_in[4];
    const float* b2        = (const float*)d_in[5];
    const int*   senders   = (const int*)d_in[6];
    const int*   receivers = (const int*)d_in[7];
    float* out = (float*)d_out;

    unsigned short* w1t = (unsigned short*)d_ws;
    unsigned short* w2t = w1t + DIN * DHID;
    unsigned short* vfb = w2t + DHID * DOUT;
    const size_t need_vfb = (size_t)(DIN * DHID + DHID * DOUT + NV * DV) * sizeof(unsigned short);
    const bool use_vfb = ws_size >= need_vfb;

    prep_kernel<<<512, 256, 0, stream>>>(W1, W2, vfeat, w1t, w2t, vfb, use_vfb ? 1 : 0);
    if (use_vfb)
        edge_mlp<true><<<1536, 256, 0, stream>>>(edata, vfeat, b1, b2, senders, receivers,
                                                 w1t, w2t, vfb, out);
    else
        edge_mlp<false><<<1536, 256, 0, stream>>>(edata, vfeat, b1, b2, senders, receivers,
                                                  w1t, w2t, vfb, out);
}